// Round 1
// baseline (1340.843 us; speedup 1.0000x reference)
//
#include <hip/hip_runtime.h>
#include <math.h>

#define NROW 4096
#define DIM  1024
#define APP  256

__device__ __forceinline__ float wave_reduce_sum(float v) {
    #pragma unroll
    for (int off = 32; off > 0; off >>= 1) v += __shfl_xor(v, off);
    return v;
}
__device__ __forceinline__ float wave_reduce_max(float v) {
    #pragma unroll
    for (int off = 32; off > 0; off >>= 1) v = fmaxf(v, __shfl_xor(v, off));
    return v;
}

// C[M,N] = act(alpha * A@B + bias); A row-major [M,K], B row-major [K,N].
// 64x64 tile, 256 threads, 4x4 microtile per thread.
__global__ __launch_bounds__(256) void gemm_kernel(
    const float* __restrict__ A, const float* __restrict__ B, float* __restrict__ C,
    int M, int N, int K, float alpha, const float* __restrict__ bias, int relu)
{
    __shared__ float As[64][17];   // +1 pad breaks bank aliasing on column reads
    __shared__ float Bs[16][64];

    const int t  = threadIdx.x;
    const int tx = t & 15, ty = t >> 4;
    const int arow = t >> 2,  acol = (t & 3) << 2;    // A tile: 64 rows x 16 k
    const int brow = t >> 4,  bcol = (t & 15) << 2;   // B tile: 16 k x 64 cols

    const float* Ab = A + (size_t)(blockIdx.y * 64) * K;
    const float* Bb = B + blockIdx.x * 64;

    float acc[4][4] = {};

    for (int kk = 0; kk < K; kk += 16) {
        float4 av = *(const float4*)(Ab + (size_t)arow * K + kk + acol);
        As[arow][acol + 0] = av.x; As[arow][acol + 1] = av.y;
        As[arow][acol + 2] = av.z; As[arow][acol + 3] = av.w;
        float4 bv = *(const float4*)(Bb + (size_t)(kk + brow) * N + bcol);
        *(float4*)(&Bs[brow][bcol]) = bv;
        __syncthreads();
        #pragma unroll
        for (int k = 0; k < 16; ++k) {
            float a0 = As[ty * 4 + 0][k], a1 = As[ty * 4 + 1][k];
            float a2 = As[ty * 4 + 2][k], a3 = As[ty * 4 + 3][k];
            float b0 = Bs[k][tx * 4 + 0], b1 = Bs[k][tx * 4 + 1];
            float b2 = Bs[k][tx * 4 + 2], b3 = Bs[k][tx * 4 + 3];
            acc[0][0] += a0 * b0; acc[0][1] += a0 * b1; acc[0][2] += a0 * b2; acc[0][3] += a0 * b3;
            acc[1][0] += a1 * b0; acc[1][1] += a1 * b1; acc[1][2] += a1 * b2; acc[1][3] += a1 * b3;
            acc[2][0] += a2 * b0; acc[2][1] += a2 * b1; acc[2][2] += a2 * b2; acc[2][3] += a2 * b3;
            acc[3][0] += a3 * b0; acc[3][1] += a3 * b1; acc[3][2] += a3 * b2; acc[3][3] += a3 * b3;
        }
        __syncthreads();
    }

    const int col = blockIdx.x * 64 + tx * 4;
    float bv[4] = {0.f, 0.f, 0.f, 0.f};
    if (bias) {
        bv[0] = bias[col + 0]; bv[1] = bias[col + 1];
        bv[2] = bias[col + 2]; bv[3] = bias[col + 3];
    }
    #pragma unroll
    for (int i = 0; i < 4; ++i) {
        int row = blockIdx.y * 64 + ty * 4 + i;
        float4 o;
        o.x = alpha * acc[i][0] + bv[0];
        o.y = alpha * acc[i][1] + bv[1];
        o.z = alpha * acc[i][2] + bv[2];
        o.w = alpha * acc[i][3] + bv[3];
        if (relu) {
            o.x = fmaxf(o.x, 0.f); o.y = fmaxf(o.y, 0.f);
            o.z = fmaxf(o.z, 0.f); o.w = fmaxf(o.w, 0.f);
        }
        *(float4*)(C + (size_t)row * N + col) = o;
    }
}

// One block per output column j. logits[i] = Q[i].K[j] for i in band,
// softmax over i, Y[j] = sum_i w_i V[i].
__global__ __launch_bounds__(256) void attn_kernel(
    const float* __restrict__ Q, const float* __restrict__ Km,
    const float* __restrict__ V, float* __restrict__ Y)
{
    __shared__ float kj[DIM];
    __shared__ float w[520];
    __shared__ float redm[4], reds[4];

    const int j = blockIdx.x;
    const int t = threadIdx.x;
    const int lane = t & 63, wave = t >> 6;

    ((float4*)kj)[t] = ((const float4*)(Km + (size_t)j * DIM))[t];

    int ilo = j - APP; if (ilo < 0) ilo = 0;
    int ihi = j + APP; if (ihi > NROW - 1) ihi = NROW - 1;
    const int cnt = ihi - ilo + 1;
    __syncthreads();

    // one wave per band row: lanes split the 1024-dot, shuffle-reduce
    for (int ii = wave; ii < cnt; ii += 4) {
        const float* qr = Q + (size_t)(ilo + ii) * DIM;
        float s = 0.f;
        #pragma unroll
        for (int c = 0; c < 16; ++c) {
            int k = lane + (c << 6);
            s += qr[k] * kj[k];
        }
        s = wave_reduce_sum(s);
        if (lane == 0) w[ii] = s;
    }
    __syncthreads();

    // softmax over the band
    float m = -1e30f;
    for (int ii = t; ii < cnt; ii += 256) m = fmaxf(m, w[ii]);
    m = wave_reduce_max(m);
    if (lane == 0) redm[wave] = m;
    __syncthreads();
    m = fmaxf(fmaxf(redm[0], redm[1]), fmaxf(redm[2], redm[3]));

    float s = 0.f;
    for (int ii = t; ii < cnt; ii += 256) {
        float e = __expf(w[ii] - m);
        w[ii] = e;
        s += e;
    }
    s = wave_reduce_sum(s);
    if (lane == 0) reds[wave] = s;
    __syncthreads();
    const float inv = 1.f / (reds[0] + reds[1] + reds[2] + reds[3]);

    // Y[j] = sum_i w_i * V[i]; threads split the 1024 columns
    float acc[4] = {0.f, 0.f, 0.f, 0.f};
    for (int ii = 0; ii < cnt; ++ii) {
        float wi = w[ii];
        const float* vr = V + (size_t)(ilo + ii) * DIM;
        #pragma unroll
        for (int c = 0; c < 4; ++c) acc[c] += wi * vr[t + (c << 8)];
    }
    float* yr = Y + (size_t)j * DIM;
    #pragma unroll
    for (int c = 0; c < 4; ++c) yr[t + (c << 8)] = acc[c] * inv;
}

// O[r] = LN(T[r] (+ X[r])) * g + b ; one block per row
__global__ __launch_bounds__(256) void add_ln_kernel(
    const float* __restrict__ T, const float* __restrict__ X,
    const float* __restrict__ g, const float* __restrict__ b, float* __restrict__ O)
{
    __shared__ float red1[4], red2[4];
    const int r = blockIdx.x, t = threadIdx.x;
    const int lane = t & 63, wave = t >> 6;
    const float* tr = T + (size_t)r * DIM;

    float v[4];
    float s = 0.f;
    #pragma unroll
    for (int c = 0; c < 4; ++c) {
        int d = t + (c << 8);
        v[c] = tr[d] + (X ? X[(size_t)r * DIM + d] : 0.f);
        s += v[c];
    }
    s = wave_reduce_sum(s);
    if (lane == 0) red1[wave] = s;
    __syncthreads();
    const float mu = (red1[0] + red1[1] + red1[2] + red1[3]) * (1.f / DIM);

    float s2 = 0.f;
    #pragma unroll
    for (int c = 0; c < 4; ++c) { float dd = v[c] - mu; s2 += dd * dd; }
    s2 = wave_reduce_sum(s2);
    if (lane == 0) red2[wave] = s2;
    __syncthreads();
    const float var = (red2[0] + red2[1] + red2[2] + red2[3]) * (1.f / DIM);
    const float rstd = rsqrtf(var + 1e-3f);

    #pragma unroll
    for (int c = 0; c < 4; ++c) {
        int d = t + (c << 8);
        O[(size_t)r * DIM + d] = (v[c] - mu) * rstd * g[d] + b[d];
    }
}

// out[r] = sigmoid(Y[r].wkd + bkd); one wave per row
__global__ __launch_bounds__(256) void final_kernel(
    const float* __restrict__ Y, const float* __restrict__ wkd,
    const float* __restrict__ bkd, float* __restrict__ out)
{
    const int lane = threadIdx.x & 63, wave = threadIdx.x >> 6;
    const int r = blockIdx.x * 4 + wave;
    const float* yr = Y + (size_t)r * DIM;
    float s = 0.f;
    #pragma unroll
    for (int c = 0; c < 16; ++c) {
        int k = lane + (c << 6);
        s += yr[k] * wkd[k];
    }
    s = wave_reduce_sum(s);
    if (lane == 0) out[r] = 1.f / (1.f + __expf(-(s + bkd[0])));
}

extern "C" void kernel_launch(void* const* d_in, const int* in_sizes, int n_in,
                              void* d_out, int out_size, void* d_ws, size_t ws_size,
                              hipStream_t stream) {
    const float* x    = (const float*)d_in[0];
    const float* wk   = (const float*)d_in[1];
    const float* wq   = (const float*)d_in[2];
    const float* wv   = (const float*)d_in[3];
    const float* wo   = (const float*)d_in[4];
    const float* wka  = (const float*)d_in[5];
    const float* bka  = (const float*)d_in[6];
    const float* wkd  = (const float*)d_in[7];
    const float* bkd  = (const float*)d_in[8];
    const float* g_y  = (const float*)d_in[9];
    const float* b_y  = (const float*)d_in[10];
    const float* g_ka = (const float*)d_in[11];
    const float* b_ka = (const float*)d_in[12];
    float* out = (float*)d_out;

    const size_t NM = (size_t)NROW * DIM;   // 4M floats = 16 MB
    float* fK = (float*)d_ws;
    float* fQ = fK + NM;
    float* fV = fQ + NM;
    float* fY = fV + NM;                    // total 64 MB of ws

    dim3 gg(DIM / 64, NROW / 64), gb(256);

    gemm_kernel<<<gg, gb, 0, stream>>>(x, wk, fK, NROW, DIM, DIM, 1.0f,  nullptr, 0);
    gemm_kernel<<<gg, gb, 0, stream>>>(x, wq, fQ, NROW, DIM, DIM, 0.06f, nullptr, 0);
    gemm_kernel<<<gg, gb, 0, stream>>>(x, wv, fV, NROW, DIM, DIM, 1.0f,  nullptr, 0);

    attn_kernel<<<NROW, gb, 0, stream>>>(fQ, fK, fV, fY);

    // t = Y @ wo  -> fQ (Q dead)
    gemm_kernel<<<gg, gb, 0, stream>>>(fY, wo, fQ, NROW, DIM, DIM, 1.0f, nullptr, 0);
    // LN(t + x)   -> fK (K dead)
    add_ln_kernel<<<NROW, gb, 0, stream>>>(fQ, x, g_y, b_y, fK);
    // relu(. @ wka + bka) -> fV (V dead)
    gemm_kernel<<<gg, gb, 0, stream>>>(fK, wka, fV, NROW, DIM, DIM, 1.0f, bka, 1);
    // LN -> fQ
    add_ln_kernel<<<NROW, gb, 0, stream>>>(fV, nullptr, g_ka, b_ka, fQ);
    // sigmoid(. @ wkd + bkd) -> out
    final_kernel<<<NROW / 4, gb, 0, stream>>>(fQ, wkd, bkd, out);
}

// Round 2
// 199.816 us; speedup vs baseline: 6.7104x; 6.7104x over previous
//
#include <hip/hip_runtime.h>
#include <hip/hip_bf16.h>
#include <math.h>

typedef __hip_bfloat16 bf16;
typedef __attribute__((ext_vector_type(8))) short bf16x8;   // MFMA A/B frag (8 bf16)
typedef __attribute__((ext_vector_type(4))) float f32x4;    // MFMA C/D frag

#define NROW 4096
#define DIM  1024
#define APP  256

__device__ __forceinline__ unsigned short f2bu(float f) {
    bf16 h = __float2bfloat16(f);
    return *reinterpret_cast<unsigned short*>(&h);
}
__device__ __forceinline__ float bu2f(unsigned short u) {
    bf16 h; *reinterpret_cast<unsigned short*>(&h) = u;
    return __bfloat162float(h);
}
__device__ __forceinline__ unsigned pk2(float a, float b) {
    return (unsigned)f2bu(a) | ((unsigned)f2bu(b) << 16);
}
__device__ __forceinline__ void gload_lds16(const void* g, void* l) {
    __builtin_amdgcn_global_load_lds(
        (const __attribute__((address_space(1))) unsigned int*)g,
        (__attribute__((address_space(3))) unsigned int*)l, 16, 0, 0);
}

// ---------------- fp32 -> bf16 cast of x ----------------
__global__ __launch_bounds__(256) void cast_x_kernel(const float* __restrict__ x,
                                                     bf16* __restrict__ xb) {
    int idx = blockIdx.x * 256 + threadIdx.x;
    float4 v = ((const float4*)x)[idx];
    uint2 o; o.x = pk2(v.x, v.y); o.y = pk2(v.z, v.w);
    ((uint2*)xb)[idx] = o;
}

// ---------------- transpose+cast the 5 weight matrices ----------------
struct WPtrs { const float* s[5]; bf16* d[5]; };
__global__ __launch_bounds__(256) void tcast_kernel(WPtrs p) {
    __shared__ float T[64][65];
    const float* in = p.s[blockIdx.z];
    bf16* out = p.d[blockIdx.z];
    const int t = threadIdx.x;
    const int r0 = blockIdx.x * 64, c0 = blockIdx.y * 64;
    #pragma unroll
    for (int c = 0; c < 4; ++c) {
        int row = (t >> 4) + c * 16, col = (t & 15) * 4;
        float4 v = *(const float4*)(in + (size_t)(r0 + row) * 1024 + c0 + col);
        T[row][col] = v.x; T[row][col + 1] = v.y; T[row][col + 2] = v.z; T[row][col + 3] = v.w;
    }
    __syncthreads();
    #pragma unroll
    for (int c = 0; c < 4; ++c) {
        int orow = (t >> 4) + c * 16, ocol = (t & 15) * 4;
        uint2 o;
        o.x = pk2(T[ocol][orow], T[ocol + 1][orow]);
        o.y = pk2(T[ocol + 2][orow], T[ocol + 3][orow]);
        *(uint2*)(out + (size_t)(c0 + orow) * 1024 + r0 + ocol) = o;
    }
}

// ---------------- bf16 MFMA GEMM: C[M,N] = act(alpha*A@Bt^T + bias) ----------------
// A row-major [M,K]; Bt row-major [N,K] (i.e. B transposed). 128x128 tile, BK=64,
// 4 waves (2x2), XOR-swizzled LDS, global_load_lds with pre-swizzled source.
__global__ __launch_bounds__(256) void gemm_bt(
    const bf16* __restrict__ A, const bf16* __restrict__ Bt, bf16* __restrict__ C,
    int M, int N, int K, float alpha, const float* __restrict__ bias, int relu)
{
    __shared__ bf16 As[128 * 64];
    __shared__ bf16 Bs[128 * 64];
    const int t = threadIdx.x, l = t & 63, w = t >> 6;
    const int wr = w >> 1, wc = w & 1;
    const int jl = l & 15, g = l >> 4;
    const int m0 = blockIdx.y * 128, n0 = blockIdx.x * 128;

    f32x4 acc[4][4];
    #pragma unroll
    for (int i = 0; i < 4; ++i)
        #pragma unroll
        for (int j = 0; j < 4; ++j) acc[i][j] = (f32x4){0.f, 0.f, 0.f, 0.f};

    for (int kk = 0; kk < K; kk += 64) {
        __syncthreads();
        #pragma unroll
        for (int c = 0; c < 4; ++c) {
            int q = t + c * 256;
            int row = q >> 3;                       // 0..127
            int kel = ((q & 7) ^ (row & 7)) << 3;   // pre-swizzled source k-offset
            gload_lds16(A + (size_t)(m0 + row) * K + kk + kel,
                        (char*)As + (c * 256 + w * 64) * 16);
            gload_lds16(Bt + (size_t)(n0 + row) * K + kk + kel,
                        (char*)Bs + (c * 256 + w * 64) * 16);
        }
        __syncthreads();
        #pragma unroll
        for (int ks = 0; ks < 2; ++ks) {
            bf16x8 af[4], bfr[4];
            #pragma unroll
            for (int i = 0; i < 4; ++i) {
                int ra = wr * 64 + i * 16 + jl;
                af[i] = *(const bf16x8*)((char*)As + ra * 128 + ((ks * 64 + g * 16) ^ ((ra & 7) << 4)));
                int rb = wc * 64 + i * 16 + jl;
                bfr[i] = *(const bf16x8*)((char*)Bs + rb * 128 + ((ks * 64 + g * 16) ^ ((rb & 7) << 4)));
            }
            #pragma unroll
            for (int i = 0; i < 4; ++i)
                #pragma unroll
                for (int j = 0; j < 4; ++j)
                    acc[i][j] = __builtin_amdgcn_mfma_f32_16x16x32_bf16(af[i], bfr[j], acc[i][j], 0, 0, 0);
        }
    }

    const int g4 = g * 4;
    #pragma unroll
    for (int j = 0; j < 4; ++j) {
        int col = n0 + wc * 64 + j * 16 + jl;
        float bv = bias ? bias[col] : 0.f;
        #pragma unroll
        for (int i = 0; i < 4; ++i) {
            int rowb = m0 + wr * 64 + i * 16 + g4;
            #pragma unroll
            for (int r = 0; r < 4; ++r) {
                float vv = alpha * acc[i][j][r] + bv;
                if (relu) vv = fmaxf(vv, 0.f);
                C[(size_t)(rowb + r) * N + col] = __float2bfloat16(vv);
            }
        }
    }
}

// ---------------- banded attention, MFMA, roles swapped ----------------
// KQ: [4096][2048] bf16, cols 0..1023 = K, 1024..2047 = Q(unscaled).
// Vt: [1024][4096] bf16 (V transposed). Y: [4096][1024] bf16.
// Block = 16 output rows j. i-band window of 576 (36 frags, 9 per wave).
#define KQS 2048
__global__ __launch_bounds__(256) void attn_mfma(
    const bf16* __restrict__ KQ, const bf16* __restrict__ Vt, bf16* __restrict__ Y)
{
    __shared__ bf16 Ks[16 * 1024];      // swizzled K rows (32 KB)
    __shared__ bf16 Pl[576 * 16];       // P in b-frag layout: [(i>>3)][j][i&7]
    __shared__ float redm[4][16], reds[4][16];

    const int t = threadIdx.x, l = t & 63, w = t >> 6;
    const int g = l >> 4, jl = l & 15;
    const int j0 = blockIdx.x * 16;
    const int ib0 = j0 - 256;
    const bf16* Qb = KQ + 1024;

    // stage K rows j0..j0+15 (full depth 1024) into LDS, XOR-swizzled
    #pragma unroll
    for (int c = 0; c < 8; ++c) {
        int q = t + c * 256;
        int row = q >> 7;
        int kb = (q & 127) << 4;        // byte offset within row (0..2047)
        uint4 v = *(const uint4*)((const char*)(KQ + (size_t)(j0 + row) * KQS) + kb);
        *(uint4*)((char*)Ks + row * 2048 + (kb ^ ((row & 7) << 4))) = v;
    }
    __syncthreads();

    // ---- S^T fragments: sacc[f] holds S[i][j] block, i = ib0 + (w*9+f)*16 + ... ----
    int irows[9];
    #pragma unroll
    for (int f = 0; f < 9; ++f) {
        int ir = ib0 + (w * 9 + f) * 16 + jl;
        irows[f] = min(max(ir, 0), NROW - 1);   // clamp addr; value masked later
    }

    f32x4 sacc[9];
    #pragma unroll
    for (int f = 0; f < 9; ++f) sacc[f] = (f32x4){0.f, 0.f, 0.f, 0.f};

    bf16x8 bcur = *(const bf16x8*)((const char*)Ks + jl * 2048 + ((g * 16) ^ ((jl & 7) << 4)));
    bf16x8 acur[9];
    #pragma unroll
    for (int f = 0; f < 9; ++f)
        acur[f] = *(const bf16x8*)(Qb + (size_t)irows[f] * KQS + g * 8);

    for (int kk = 0; kk < DIM - 32; kk += 32) {
        int k2 = kk + 32;
        bf16x8 bn = *(const bf16x8*)((const char*)Ks + jl * 2048 + ((k2 * 2 + g * 16) ^ ((jl & 7) << 4)));
        bf16x8 an[9];
        #pragma unroll
        for (int f = 0; f < 9; ++f)
            an[f] = *(const bf16x8*)(Qb + (size_t)irows[f] * KQS + k2 + g * 8);
        #pragma unroll
        for (int f = 0; f < 9; ++f)
            sacc[f] = __builtin_amdgcn_mfma_f32_16x16x32_bf16(acur[f], bcur, sacc[f], 0, 0, 0);
        bcur = bn;
        #pragma unroll
        for (int f = 0; f < 9; ++f) acur[f] = an[f];
    }
    #pragma unroll
    for (int f = 0; f < 9; ++f)
        sacc[f] = __builtin_amdgcn_mfma_f32_16x16x32_bf16(acur[f], bcur, sacc[f], 0, 0, 0);

    // ---- masked softmax over i, per column j = j0 + jl (lane-local) ----
    float mv[9][4];
    float mx = -3e38f;
    #pragma unroll
    for (int f = 0; f < 9; ++f) {
        #pragma unroll
        for (int r = 0; r < 4; ++r) {
            int ioff = (w * 9 + f) * 16 + g * 4 + r;
            int i = ib0 + ioff;
            int dd = i - (j0 + jl);
            bool ok = (i >= 0) && (i < NROW) && (dd >= -APP) && (dd <= APP);
            float vv = ok ? sacc[f][r] * 0.06f : -3e38f;   // fold Q scale here
            mv[f][r] = vv;
            mx = fmaxf(mx, vv);
        }
    }
    mx = fmaxf(mx, __shfl_xor(mx, 16));
    mx = fmaxf(mx, __shfl_xor(mx, 32));
    if (l < 16) redm[w][l] = mx;
    __syncthreads();
    float M = fmaxf(fmaxf(redm[0][jl], redm[1][jl]), fmaxf(redm[2][jl], redm[3][jl]));
    float sum = 0.f;
    #pragma unroll
    for (int f = 0; f < 9; ++f)
        #pragma unroll
        for (int r = 0; r < 4; ++r) {
            float e = __expf(mv[f][r] - M);
            mv[f][r] = e;
            sum += e;
        }
    sum += __shfl_xor(sum, 16);
    sum += __shfl_xor(sum, 32);
    if (l < 16) reds[w][l] = sum;
    __syncthreads();
    float inv = 1.f / (reds[0][jl] + reds[1][jl] + reds[2][jl] + reds[3][jl]);
    #pragma unroll
    for (int f = 0; f < 9; ++f) {
        uint2 p;
        p.x = pk2(mv[f][0] * inv, mv[f][1] * inv);
        p.y = pk2(mv[f][2] * inv, mv[f][3] * inv);
        int chunk = (w * 9 + f) * 2 + (g >> 1);
        *(uint2*)((char*)Pl + chunk * 256 + jl * 16 + (g & 1) * 8) = p;
    }
    __syncthreads();

    // ---- Y^T = Vt @ P : wave w owns d in [w*256, w*256+256), two halves of 8 frags ----
    #pragma unroll
    for (int half = 0; half < 2; ++half) {
        const int db = w * 256 + half * 128;
        f32x4 yacc[8];
        #pragma unroll
        for (int df = 0; df < 8; ++df) yacc[df] = (f32x4){0.f, 0.f, 0.f, 0.f};

        bf16x8 pcur = *(const bf16x8*)((const char*)Pl + g * 256 + jl * 16);
        bf16x8 vcur[8];
        #pragma unroll
        for (int df = 0; df < 8; ++df)
            vcur[df] = *(const bf16x8*)(Vt + (ptrdiff_t)(db + df * 16 + jl) * NROW + ib0 + g * 8);

        for (int st = 0; st < 17; ++st) {
            bf16x8 pn = *(const bf16x8*)((const char*)Pl + ((st + 1) * 4 + g) * 256 + jl * 16);
            bf16x8 vn[8];
            #pragma unroll
            for (int df = 0; df < 8; ++df)
                vn[df] = *(const bf16x8*)(Vt + (ptrdiff_t)(db + df * 16 + jl) * NROW + ib0 + (st + 1) * 32 + g * 8);
            #pragma unroll
            for (int df = 0; df < 8; ++df)
                yacc[df] = __builtin_amdgcn_mfma_f32_16x16x32_bf16(vcur[df], pcur, yacc[df], 0, 0, 0);
            pcur = pn;
            #pragma unroll
            for (int df = 0; df < 8; ++df) vcur[df] = vn[df];
        }
        #pragma unroll
        for (int df = 0; df < 8; ++df)
            yacc[df] = __builtin_amdgcn_mfma_f32_16x16x32_bf16(vcur[df], pcur, yacc[df], 0, 0, 0);

        #pragma unroll
        for (int df = 0; df < 8; ++df) {
            int d = db + df * 16 + g * 4;
            uint2 o;
            o.x = pk2(yacc[df][0], yacc[df][1]);
            o.y = pk2(yacc[df][2], yacc[df][3]);
            *(uint2*)(Y + (size_t)(j0 + jl) * DIM + d) = o;
        }
    }
}

// ---------------- LayerNorm: O = LN(T (+X)) * g + b, bf16 in/out ----------------
__global__ __launch_bounds__(256) void ln_kernel(
    const bf16* __restrict__ T, const float* __restrict__ X,
    const float* __restrict__ g, const float* __restrict__ b, bf16* __restrict__ O)
{
    __shared__ float red1[4], red2[4];
    const int r = blockIdx.x, t = threadIdx.x, lane = t & 63, w = t >> 6;
    ushort4 tv = ((const ushort4*)(T + (size_t)r * DIM))[t];
    float v0 = bu2f(tv.x), v1 = bu2f(tv.y), v2 = bu2f(tv.z), v3 = bu2f(tv.w);
    if (X) {
        float4 xv = ((const float4*)(X + (size_t)r * DIM))[t];
        v0 += xv.x; v1 += xv.y; v2 += xv.z; v3 += xv.w;
    }
    float s = v0 + v1 + v2 + v3;
    #pragma unroll
    for (int off = 32; off > 0; off >>= 1) s += __shfl_xor(s, off);
    if (lane == 0) red1[w] = s;
    __syncthreads();
    float mu = (red1[0] + red1[1] + red1[2] + red1[3]) * (1.f / DIM);
    float d0 = v0 - mu, d1 = v1 - mu, d2 = v2 - mu, d3 = v3 - mu;
    float s2 = d0 * d0 + d1 * d1 + d2 * d2 + d3 * d3;
    #pragma unroll
    for (int off = 32; off > 0; off >>= 1) s2 += __shfl_xor(s2, off);
    if (lane == 0) red2[w] = s2;
    __syncthreads();
    float var = (red2[0] + red2[1] + red2[2] + red2[3]) * (1.f / DIM);
    float rstd = rsqrtf(var + 1e-3f);
    float4 gv = ((const float4*)g)[t];
    float4 bv = ((const float4*)b)[t];
    uint2 o;
    o.x = pk2(d0 * rstd * gv.x + bv.x, d1 * rstd * gv.y + bv.y);
    o.y = pk2(d2 * rstd * gv.z + bv.z, d3 * rstd * gv.w + bv.w);
    ((uint2*)(O + (size_t)r * DIM))[t] = o;
}

// ---------------- out[r] = sigmoid(Y[r].wkd + bkd) ----------------
__global__ __launch_bounds__(256) void final_kernel(
    const bf16* __restrict__ Y, const float* __restrict__ wkd,
    const float* __restrict__ bkd, float* __restrict__ out)
{
    const int lane = threadIdx.x & 63, w = threadIdx.x >> 6;
    const int r = blockIdx.x * 4 + w;
    const bf16* yr = Y + (size_t)r * DIM;
    float s = 0.f;
    #pragma unroll
    for (int c = 0; c < 4; ++c) {
        ushort4 yv = ((const ushort4*)yr)[lane * 4 + c];
        float4 wv = ((const float4*)wkd)[lane * 4 + c];
        s += bu2f(yv.x) * wv.x + bu2f(yv.y) * wv.y + bu2f(yv.z) * wv.z + bu2f(yv.w) * wv.w;
    }
    #pragma unroll
    for (int off = 32; off > 0; off >>= 1) s += __shfl_xor(s, off);
    if (lane == 0) out[r] = 1.f / (1.f + __expf(-(s + bkd[0])));
}

extern "C" void kernel_launch(void* const* d_in, const int* in_sizes, int n_in,
                              void* d_out, int out_size, void* d_ws, size_t ws_size,
                              hipStream_t stream) {
    const float* x    = (const float*)d_in[0];
    const float* wk   = (const float*)d_in[1];
    const float* wq   = (const float*)d_in[2];
    const float* wv   = (const float*)d_in[3];
    const float* wo   = (const float*)d_in[4];
    const float* wka  = (const float*)d_in[5];
    const float* bka  = (const float*)d_in[6];
    const float* wkd  = (const float*)d_in[7];
    const float* bkd  = (const float*)d_in[8];
    const float* g_y  = (const float*)d_in[9];
    const float* b_y  = (const float*)d_in[10];
    const float* g_ka = (const float*)d_in[11];
    const float* b_ka = (const float*)d_in[12];
    float* out = (float*)d_out;

    char* ws = (char*)d_ws;
    const size_t NM2 = (size_t)NROW * DIM * 2;   // 8 MB
    const size_t WT2 = (size_t)DIM * DIM * 2;    // 2 MB
    bf16* xb   = (bf16*)(ws);                        // 8 MB
    bf16* wkT  = (bf16*)(ws + NM2);                  // 2 MB (rows 0..1023 of W2T)
    bf16* wqT  = (bf16*)(ws + NM2 + WT2);            // 2 MB (rows 1024..2047, contiguous after wkT)
    bf16* wvT  = (bf16*)(ws + NM2 + 2 * WT2);        // 2 MB
    bf16* woT  = (bf16*)(ws + NM2 + 3 * WT2);        // 2 MB
    bf16* wkaT = (bf16*)(ws + NM2 + 4 * WT2);        // 2 MB
    bf16* fKQ  = (bf16*)(ws + NM2 + 5 * WT2);        // 16 MB [4096][2048]
    bf16* fVt  = (bf16*)(ws + 3 * NM2 + 5 * WT2);    // 8 MB  [1024][4096]
    bf16* fY   = (bf16*)(ws + 4 * NM2 + 5 * WT2);    // 8 MB  [4096][1024]
    bf16* fT   = fKQ;                                 // reuse after attention
    bf16* fL1  = fKQ + (size_t)NROW * DIM;            // second half of fKQ

    cast_x_kernel<<<NROW * DIM / 4 / 256, 256, 0, stream>>>(x, xb);
    WPtrs wp;
    wp.s[0] = wk;  wp.s[1] = wq;  wp.s[2] = wv;  wp.s[3] = wo;  wp.s[4] = wka;
    wp.d[0] = wkT; wp.d[1] = wqT; wp.d[2] = wvT; wp.d[3] = woT; wp.d[4] = wkaT;
    tcast_kernel<<<dim3(16, 16, 5), 256, 0, stream>>>(wp);

    // fused K|Q GEMM: [4096][2048] = xb @ [wkT;wqT]^T   (grid 512 blocks)
    gemm_bt<<<dim3(2048 / 128, NROW / 128), 256, 0, stream>>>(xb, wkT, fKQ, NROW, 2048, DIM, 1.f, nullptr, 0);
    // Vt = wvT @ xb^T : [1024][4096]
    gemm_bt<<<dim3(NROW / 128, DIM / 128), 256, 0, stream>>>(wvT, xb, fVt, DIM, NROW, DIM, 1.f, nullptr, 0);

    attn_mfma<<<NROW / 16, 256, 0, stream>>>(fKQ, fVt, fY);

    gemm_bt<<<dim3(DIM / 128, NROW / 128), 256, 0, stream>>>(fY, woT, fT, NROW, DIM, DIM, 1.f, nullptr, 0);
    ln_kernel<<<NROW, 256, 0, stream>>>(fT, x, g_y, b_y, fL1);
    gemm_bt<<<dim3(DIM / 128, NROW / 128), 256, 0, stream>>>(fL1, wkaT, fVt, NROW, DIM, DIM, 1.f, bka, 1);
    ln_kernel<<<NROW, 256, 0, stream>>>(fVt, nullptr, g_ka, b_ka, fT);
    final_kernel<<<NROW / 4, 256, 0, stream>>>(fT, wkd, bkd, out);
}